// Round 1
// 317.423 us; speedup vs baseline: 1.3306x; 1.3306x over previous
//
#include <hip/hip_runtime.h>

#define N_NODES_C 100000
#define D_FEAT 64
#define BSHIFT 5
#define BSIZE 32                                        // nodes per bucket
#define NBUCKETS ((N_NODES_C + BSIZE - 1) / BSIZE)      // 3125
#define COL_MASK 0xFFFFF                                // col < 2^20
#define STASH_CAP 1024

// ---------------- fallback (round-1) atomic kernel ----------------
__global__ void spline_scatter_atomic(const float* __restrict__ x,
                                      const int* __restrict__ row_idx,
                                      const int* __restrict__ col_idx,
                                      const float* __restrict__ edge_attr,
                                      float* __restrict__ out,
                                      int n_edges) {
    long long t = (long long)blockIdx.x * blockDim.x + threadIdx.x;
    int e = (int)(t >> 6);
    int f = (int)(t & 63);
    if (e >= n_edges) return;
    int r = row_idx[e];
    int c = col_idx[e];
    float w = expf(-edge_attr[e]);
    atomicAdd(&out[(long long)r * D_FEAT + f], w * x[(long long)c * D_FEAT + f]);
}

// ---------------- legacy CSR-build pipeline (fallback #2) ----------------

__global__ void hist_kernel(const int* __restrict__ row_idx, int* __restrict__ counts,
                            int n_edges) {
    int e = blockIdx.x * blockDim.x + threadIdx.x;
    if (e < n_edges) atomicAdd(&counts[row_idx[e]], 1);
}

// single-block exclusive scan of counts[n] -> start[n+1], cursor[n]
__global__ void scan_kernel(const int* __restrict__ counts, int* __restrict__ start,
                            int* __restrict__ cursor, int n) {
    __shared__ int wave_sums[16];
    __shared__ int carry_s;
    const int tid = threadIdx.x;          // 1024 threads = 16 waves
    const int lane = tid & 63;
    const int wid = tid >> 6;
    if (tid == 0) carry_s = 0;
    __syncthreads();
    for (int base = 0; base < n; base += 1024) {
        int i = base + tid;
        int v = (i < n) ? counts[i] : 0;
        int inc = v;
        #pragma unroll
        for (int d = 1; d < 64; d <<= 1) {
            int t = __shfl_up(inc, d, 64);
            if (lane >= d) inc += t;
        }
        if (lane == 63) wave_sums[wid] = inc;
        __syncthreads();
        if (tid == 0) {
            int s = carry_s;
            #pragma unroll
            for (int k = 0; k < 16; ++k) { int t = wave_sums[k]; wave_sums[k] = s; s += t; }
            carry_s = s;
        }
        __syncthreads();
        int excl = inc - v + wave_sums[wid];
        if (i < n) { start[i] = excl; cursor[i] = excl; }
        __syncthreads();
    }
    if (tid == 0) start[n] = carry_s;
}

__global__ void bucket_kernel(const int* __restrict__ row_idx,
                              const int* __restrict__ col_idx,
                              const float* __restrict__ edge_attr,
                              int* __restrict__ cursor,
                              int2* __restrict__ colw,
                              int n_edges) {
    int e = blockIdx.x * blockDim.x + threadIdx.x;
    if (e >= n_edges) return;
    int r = row_idx[e];
    int c = col_idx[e];
    float w = expf(-edge_attr[e]);
    int pos = atomicAdd(&cursor[r], 1);
    colw[pos] = make_int2(c, __float_as_int(w));
}

// ---------------- new two-level bucket pipeline ----------------

// K1: coarse histogram over NBUCKETS, LDS-aggregated
__global__ __launch_bounds__(1024) void coarse_hist_kernel(const int* __restrict__ row,
                                                           int* __restrict__ cc,
                                                           int n_edges) {
    __shared__ int h[NBUCKETS];
    for (int i = threadIdx.x; i < NBUCKETS; i += 1024) h[i] = 0;
    __syncthreads();
    int stride = gridDim.x * 1024;
    for (int e = blockIdx.x * 1024 + threadIdx.x; e < n_edges; e += stride)
        atomicAdd(&h[row[e] >> BSHIFT], 1);
    __syncthreads();
    for (int i = threadIdx.x; i < NBUCKETS; i += 1024) {
        int v = h[i];
        if (v) atomicAdd(&cc[i], v);
    }
}

// K3: coarse scatter — append {col|lnode<<20, w} into bucket-ordered cw[].
// Appends per bucket are sequential, so the write frontier is ~3125 hot lines.
__global__ void coarse_scatter_kernel(const int* __restrict__ row,
                                      const int* __restrict__ col,
                                      const float* __restrict__ attr,
                                      int* __restrict__ ccursor,
                                      int2* __restrict__ cw,
                                      int n_edges) {
    int e = blockIdx.x * blockDim.x + threadIdx.x;
    if (e >= n_edges) return;
    int r = row[e];
    int c = col[e];
    float w = expf(-attr[e]);
    int p = atomicAdd(&ccursor[r >> BSHIFT], 1);
    cw[p] = make_int2(c | ((r & (BSIZE - 1)) << 20), __float_as_int(w));
}

// K4: fine scatter — one block per bucket. LDS hist of 32 local nodes,
// LDS scan, LDS-atomic placement. Writes a contiguous ~4KB region.
// Also emits start[] for this bucket's nodes (replaces global hist+scan).
__global__ __launch_bounds__(256) void fine_scatter_kernel(const int2* __restrict__ cw,
                                                           const int* __restrict__ cstart,
                                                           int* __restrict__ start,
                                                           int2* __restrict__ colw) {
    int b = blockIdx.x;
    int tid = threadIdx.x;
    int beg = cstart[b];
    int end = cstart[b + 1];
    int nb = end - beg;
    __shared__ int lhist[BSIZE];
    __shared__ int lcur[BSIZE];
    __shared__ int2 lcw[STASH_CAP];
    if (tid < BSIZE) lhist[tid] = 0;
    __syncthreads();
    bool stash = (nb <= STASH_CAP);
    for (int i = tid; i < nb; i += 256) {
        int2 v = cw[beg + i];
        if (stash) lcw[i] = v;
        atomicAdd(&lhist[(v.x >> 20) & (BSIZE - 1)], 1);
    }
    __syncthreads();
    if (tid == 0) {
        int s = 0;
        #pragma unroll
        for (int k = 0; k < BSIZE; ++k) {
            int t = lhist[k];
            lcur[k] = s;
            lhist[k] = s;   // lhist now holds the exclusive scan
            s += t;
        }
    }
    __syncthreads();
    if (tid < BSIZE) {
        int node = b * BSIZE + tid;
        if (node < N_NODES_C) start[node] = beg + lhist[tid];
    }
    if (b == gridDim.x - 1 && tid == 0) start[N_NODES_C] = end;
    for (int i = tid; i < nb; i += 256) {
        int2 v = stash ? lcw[i] : cw[beg + i];
        int ln = (v.x >> 20) & (BSIZE - 1);
        int p = atomicAdd(&lcur[ln], 1);
        colw[beg + p] = make_int2(v.x & COL_MASK, v.y);
    }
}

// K5: one wave per node: gather + register accumulate, single plain store
__global__ void gather_accum_kernel(const float* __restrict__ x,
                                    const int* __restrict__ start,
                                    const int2* __restrict__ colw,
                                    float* __restrict__ out,
                                    int n_nodes) {
    int node = blockIdx.x * (blockDim.x >> 6) + (threadIdx.x >> 6);
    int lane = threadIdx.x & 63;
    if (node >= n_nodes) return;
    int b = start[node];
    int e = start[node + 1];
    float acc = 0.0f;
    int j = b;
    for (; j + 3 < e; j += 4) {
        int2 c0 = colw[j], c1 = colw[j + 1], c2 = colw[j + 2], c3 = colw[j + 3];
        float x0 = x[(size_t)c0.x * D_FEAT + lane];
        float x1 = x[(size_t)c1.x * D_FEAT + lane];
        float x2 = x[(size_t)c2.x * D_FEAT + lane];
        float x3 = x[(size_t)c3.x * D_FEAT + lane];
        acc += __int_as_float(c0.y) * x0;
        acc += __int_as_float(c1.y) * x1;
        acc += __int_as_float(c2.y) * x2;
        acc += __int_as_float(c3.y) * x3;
    }
    for (; j < e; ++j) {
        int2 c0 = colw[j];
        acc += __int_as_float(c0.y) * x[(size_t)c0.x * D_FEAT + lane];
    }
    out[(size_t)node * D_FEAT + lane] = acc;
}

extern "C" void kernel_launch(void* const* d_in, const int* in_sizes, int n_in,
                              void* d_out, int out_size, void* d_ws, size_t ws_size,
                              hipStream_t stream) {
    const float* x    = (const float*)d_in[0];
    const int*   eidx = (const int*)d_in[1];   // flat (2, E): [row | col]
    const float* attr = (const float*)d_in[2];
    float*       out  = (float*)d_out;

    const int n_edges = in_sizes[2];
    const int n_nodes = N_NODES_C;
    const int* row = eidx;
    const int* col = eidx + n_edges;

    // ---------- new two-level layout ----------
    // cw     : int2[E]
    // colw   : int2[E]
    // cc     : int[NBUCKETS]
    // cstart : int[NBUCKETS+1]
    // ccursor: int[NBUCKETS]
    // start  : int[N+1]
    size_t off_cw     = 0;
    size_t off_colw   = off_cw + (size_t)n_edges * sizeof(int2);
    size_t off_cc     = off_colw + (size_t)n_edges * sizeof(int2);
    size_t off_cstart = off_cc + (size_t)NBUCKETS * sizeof(int);
    size_t off_ccur   = off_cstart + (size_t)(NBUCKETS + 1) * sizeof(int);
    size_t off_start  = off_ccur + (size_t)NBUCKETS * sizeof(int);
    size_t ws_needed_new = off_start + (size_t)(n_nodes + 1) * sizeof(int);

    if (ws_size >= ws_needed_new) {
        char* ws = (char*)d_ws;
        int2* cw      = (int2*)(ws + off_cw);
        int2* colw    = (int2*)(ws + off_colw);
        int*  cc      = (int*)(ws + off_cc);
        int*  cstart  = (int*)(ws + off_cstart);
        int*  ccursor = (int*)(ws + off_ccur);
        int*  start   = (int*)(ws + off_start);

        hipMemsetAsync(cc, 0, (size_t)NBUCKETS * sizeof(int), stream);

        const int eb = (n_edges + 255) / 256;
        coarse_hist_kernel<<<128, 1024, 0, stream>>>(row, cc, n_edges);
        scan_kernel<<<1, 1024, 0, stream>>>(cc, cstart, ccursor, NBUCKETS);
        coarse_scatter_kernel<<<eb, 256, 0, stream>>>(row, col, attr, ccursor, cw, n_edges);
        fine_scatter_kernel<<<NBUCKETS, 256, 0, stream>>>(cw, cstart, start, colw);

        const int waves_per_block = 4;                 // 256 threads
        const int nb = (n_nodes + waves_per_block - 1) / waves_per_block;
        gather_accum_kernel<<<nb, 256, 0, stream>>>(x, start, colw, out, n_nodes);
        return;
    }

    // ---------- legacy CSR layout (fallback #2) ----------
    size_t l_off_colw   = 0;
    size_t l_off_counts = l_off_colw + (size_t)n_edges * sizeof(int2);
    size_t l_off_start  = l_off_counts + (size_t)n_nodes * sizeof(int);
    size_t l_off_cursor = l_off_start + (size_t)(n_nodes + 1) * sizeof(int);
    size_t ws_needed_old = l_off_cursor + (size_t)n_nodes * sizeof(int);

    if (ws_size >= ws_needed_old) {
        char* ws = (char*)d_ws;
        int2* colw   = (int2*)(ws + l_off_colw);
        int*  counts = (int*)(ws + l_off_counts);
        int*  start  = (int*)(ws + l_off_start);
        int*  cursor = (int*)(ws + l_off_cursor);

        hipMemsetAsync(counts, 0, (size_t)n_nodes * sizeof(int), stream);

        const int eb = (n_edges + 255) / 256;
        hist_kernel<<<eb, 256, 0, stream>>>(row, counts, n_edges);
        scan_kernel<<<1, 1024, 0, stream>>>(counts, start, cursor, n_nodes);
        bucket_kernel<<<eb, 256, 0, stream>>>(row, col, attr, cursor, colw, n_edges);

        const int waves_per_block = 4;
        const int nb = (n_nodes + waves_per_block - 1) / waves_per_block;
        gather_accum_kernel<<<nb, 256, 0, stream>>>(x, start, colw, out, n_nodes);
        return;
    }

    // ---------- last resort: atomic kernel ----------
    hipMemsetAsync(out, 0, (size_t)out_size * sizeof(float), stream);
    const long long total = (long long)n_edges * 64;
    const int blocks = (int)((total + 255) / 256);
    spline_scatter_atomic<<<blocks, 256, 0, stream>>>(x, row, col, attr, out, n_edges);
}

// Round 2
// 210.882 us; speedup vs baseline: 2.0028x; 1.5052x over previous
//
#include <hip/hip_runtime.h>

#define N_NODES_C 100000
#define D_FEAT 64

// coarse bucket geometry: 512 nodes per bucket
#define CB_SHIFT 9
#define CB_SIZE 512
#define NCB ((N_NODES_C + CB_SIZE - 1) / CB_SIZE)   // 196
#define COL_BITS 17                                  // col < 100000 < 2^17
#define COL_MASK17 0x1FFFF
#define CHUNK 4096                                   // edges per agg-scatter block

// ---------------- fallback (round-1) atomic kernel ----------------
__global__ void spline_scatter_atomic(const float* __restrict__ x,
                                      const int* __restrict__ row_idx,
                                      const int* __restrict__ col_idx,
                                      const float* __restrict__ edge_attr,
                                      float* __restrict__ out,
                                      int n_edges) {
    long long t = (long long)blockIdx.x * blockDim.x + threadIdx.x;
    int e = (int)(t >> 6);
    int f = (int)(t & 63);
    if (e >= n_edges) return;
    int r = row_idx[e];
    int c = col_idx[e];
    float w = expf(-edge_attr[e]);
    atomicAdd(&out[(long long)r * D_FEAT + f], w * x[(long long)c * D_FEAT + f]);
}

// ---------------- legacy CSR-build pipeline (fallback #2) ----------------

__global__ void hist_kernel(const int* __restrict__ row_idx, int* __restrict__ counts,
                            int n_edges) {
    int e = blockIdx.x * blockDim.x + threadIdx.x;
    if (e < n_edges) atomicAdd(&counts[row_idx[e]], 1);
}

// single-block exclusive scan of counts[n] -> start[n+1], cursor[n]
__global__ void scan_kernel(const int* __restrict__ counts, int* __restrict__ start,
                            int* __restrict__ cursor, int n) {
    __shared__ int wave_sums[16];
    __shared__ int carry_s;
    const int tid = threadIdx.x;          // 1024 threads = 16 waves
    const int lane = tid & 63;
    const int wid = tid >> 6;
    if (tid == 0) carry_s = 0;
    __syncthreads();
    for (int base = 0; base < n; base += 1024) {
        int i = base + tid;
        int v = (i < n) ? counts[i] : 0;
        int inc = v;
        #pragma unroll
        for (int d = 1; d < 64; d <<= 1) {
            int t = __shfl_up(inc, d, 64);
            if (lane >= d) inc += t;
        }
        if (lane == 63) wave_sums[wid] = inc;
        __syncthreads();
        if (tid == 0) {
            int s = carry_s;
            #pragma unroll
            for (int k = 0; k < 16; ++k) { int t = wave_sums[k]; wave_sums[k] = s; s += t; }
            carry_s = s;
        }
        __syncthreads();
        int excl = inc - v + wave_sums[wid];
        if (i < n) { start[i] = excl; cursor[i] = excl; }
        __syncthreads();
    }
    if (tid == 0) start[n] = carry_s;
}

__global__ void bucket_kernel(const int* __restrict__ row_idx,
                              const int* __restrict__ col_idx,
                              const float* __restrict__ edge_attr,
                              int* __restrict__ cursor,
                              int2* __restrict__ colw,
                              int n_edges) {
    int e = blockIdx.x * blockDim.x + threadIdx.x;
    if (e >= n_edges) return;
    int r = row_idx[e];
    int c = col_idx[e];
    float w = expf(-edge_attr[e]);
    int pos = atomicAdd(&cursor[r], 1);
    colw[pos] = make_int2(c, __float_as_int(w));
}

// ---------------- two-level bucket pipeline (block-aggregated) ----------------

// K1: coarse histogram over NCB buckets, LDS-aggregated
__global__ __launch_bounds__(1024) void coarse_hist196(const int* __restrict__ row,
                                                       int* __restrict__ cc,
                                                       int n_edges) {
    __shared__ int h[NCB];
    for (int i = threadIdx.x; i < NCB; i += 1024) h[i] = 0;
    __syncthreads();
    int stride = gridDim.x * 1024;
    for (int e = blockIdx.x * 1024 + threadIdx.x; e < n_edges; e += stride)
        atomicAdd(&h[row[e] >> CB_SHIFT], 1);
    __syncthreads();
    for (int i = threadIdx.x; i < NCB; i += 1024) {
        int v = h[i];
        if (v) atomicAdd(&cc[i], v);
    }
}

// K3: block-aggregated coarse scatter.
// Each block: LDS hist over its 4096-edge chunk -> ONE global atomicAdd per
// touched bucket to reserve a contiguous segment -> scatter into own segment.
// Every 64B line of cw is written by exactly one block (one CU) -> no
// cross-XCD partial-line writeback amplification.
__global__ __launch_bounds__(256) void agg_scatter_kernel(const int* __restrict__ row,
                                                          const int* __restrict__ col,
                                                          const float* __restrict__ attr,
                                                          int* __restrict__ ccursor,
                                                          int2* __restrict__ cw,
                                                          int n_edges) {
    __shared__ int h[NCB];
    __shared__ int gbase[NCB];
    __shared__ int lcur[NCB];
    const int tid = threadIdx.x;
    const int base = blockIdx.x * CHUNK;
    for (int i = tid; i < NCB; i += 256) { h[i] = 0; lcur[i] = 0; }
    __syncthreads();
    #pragma unroll
    for (int k = 0; k < CHUNK / 256; ++k) {
        int e = base + k * 256 + tid;
        if (e < n_edges) atomicAdd(&h[row[e] >> CB_SHIFT], 1);
    }
    __syncthreads();
    for (int i = tid; i < NCB; i += 256) {
        int c = h[i];
        gbase[i] = c ? atomicAdd(&ccursor[i], c) : 0;
    }
    __syncthreads();
    #pragma unroll
    for (int k = 0; k < CHUNK / 256; ++k) {
        int e = base + k * 256 + tid;
        if (e < n_edges) {
            int r = row[e];
            int b = r >> CB_SHIFT;
            int c = col[e];
            float w = expf(-attr[e]);
            int p = gbase[b] + atomicAdd(&lcur[b], 1);
            cw[p] = make_int2(c | ((r & (CB_SIZE - 1)) << COL_BITS), __float_as_int(w));
        }
    }
}

// K4: fine scatter — one 1024-thread block per 512-node bucket (~8192 edges).
// LDS hist[512] + shfl scan + LDS-cursor placement into the bucket's
// contiguous window. Also emits start[] (no global per-node hist/scan needed).
__global__ __launch_bounds__(1024) void fine_scatter512_kernel(const int2* __restrict__ cw,
                                                               const int* __restrict__ cstart,
                                                               int* __restrict__ start,
                                                               int2* __restrict__ colw,
                                                               int n_nodes) {
    __shared__ int lhist[CB_SIZE];
    __shared__ int lcur[CB_SIZE];
    __shared__ int wsum[16];
    const int b = blockIdx.x;
    const int tid = threadIdx.x;
    const int beg = cstart[b];
    const int end = cstart[b + 1];
    const int n = end - beg;
    if (tid < CB_SIZE) lhist[tid] = 0;
    __syncthreads();
    for (int i = tid; i < n; i += 1024) {
        int2 v = cw[beg + i];
        atomicAdd(&lhist[(v.x >> COL_BITS) & (CB_SIZE - 1)], 1);
    }
    __syncthreads();
    // exclusive scan of lhist[0..511]
    const int lane = tid & 63;
    const int wid = tid >> 6;
    int v = (tid < CB_SIZE) ? lhist[tid] : 0;
    int inc = v;
    #pragma unroll
    for (int d = 1; d < 64; d <<= 1) {
        int t = __shfl_up(inc, d, 64);
        if (lane >= d) inc += t;
    }
    if (lane == 63) wsum[wid] = inc;
    __syncthreads();
    if (tid == 0) {
        int s = 0;
        #pragma unroll
        for (int k = 0; k < 16; ++k) { int t = wsum[k]; wsum[k] = s; s += t; }
    }
    __syncthreads();
    int excl = inc - v + wsum[wid];
    if (tid < CB_SIZE) {
        lcur[tid] = beg + excl;
        int node = b * CB_SIZE + tid;
        if (node < n_nodes) start[node] = beg + excl;
    }
    if (b == gridDim.x - 1 && tid == 0) start[n_nodes] = end;
    __syncthreads();
    for (int i = tid; i < n; i += 1024) {
        int2 v2 = cw[beg + i];
        int ln = (v2.x >> COL_BITS) & (CB_SIZE - 1);
        int p = atomicAdd(&lcur[ln], 1);
        colw[p] = make_int2(v2.x & COL_MASK17, v2.y);
    }
}

// K5: one wave per node: gather + register accumulate, single plain store
__global__ void gather_accum_kernel(const float* __restrict__ x,
                                    const int* __restrict__ start,
                                    const int2* __restrict__ colw,
                                    float* __restrict__ out,
                                    int n_nodes) {
    int node = blockIdx.x * (blockDim.x >> 6) + (threadIdx.x >> 6);
    int lane = threadIdx.x & 63;
    if (node >= n_nodes) return;
    int b = start[node];
    int e = start[node + 1];
    float acc = 0.0f;
    int j = b;
    for (; j + 3 < e; j += 4) {
        int2 c0 = colw[j], c1 = colw[j + 1], c2 = colw[j + 2], c3 = colw[j + 3];
        float x0 = x[(size_t)c0.x * D_FEAT + lane];
        float x1 = x[(size_t)c1.x * D_FEAT + lane];
        float x2 = x[(size_t)c2.x * D_FEAT + lane];
        float x3 = x[(size_t)c3.x * D_FEAT + lane];
        acc += __int_as_float(c0.y) * x0;
        acc += __int_as_float(c1.y) * x1;
        acc += __int_as_float(c2.y) * x2;
        acc += __int_as_float(c3.y) * x3;
    }
    for (; j < e; ++j) {
        int2 c0 = colw[j];
        acc += __int_as_float(c0.y) * x[(size_t)c0.x * D_FEAT + lane];
    }
    out[(size_t)node * D_FEAT + lane] = acc;
}

extern "C" void kernel_launch(void* const* d_in, const int* in_sizes, int n_in,
                              void* d_out, int out_size, void* d_ws, size_t ws_size,
                              hipStream_t stream) {
    const float* x    = (const float*)d_in[0];
    const int*   eidx = (const int*)d_in[1];   // flat (2, E): [row | col]
    const float* attr = (const float*)d_in[2];
    float*       out  = (float*)d_out;

    const int n_edges = in_sizes[2];
    const int n_nodes = N_NODES_C;
    const int* row = eidx;
    const int* col = eidx + n_edges;

    // ---------- two-level layout ----------
    // cw     : int2[E]
    // colw   : int2[E]
    // cc     : int[NCB]
    // cstart : int[NCB+1]
    // ccursor: int[NCB]
    // start  : int[N+1]
    size_t off_cw     = 0;
    size_t off_colw   = off_cw + (size_t)n_edges * sizeof(int2);
    size_t off_cc     = off_colw + (size_t)n_edges * sizeof(int2);
    size_t off_cstart = off_cc + (size_t)NCB * sizeof(int);
    size_t off_ccur   = off_cstart + (size_t)(NCB + 1) * sizeof(int);
    size_t off_start  = off_ccur + (size_t)NCB * sizeof(int);
    size_t ws_needed_new = off_start + (size_t)(n_nodes + 1) * sizeof(int);

    if (ws_size >= ws_needed_new) {
        char* ws = (char*)d_ws;
        int2* cw      = (int2*)(ws + off_cw);
        int2* colw    = (int2*)(ws + off_colw);
        int*  cc      = (int*)(ws + off_cc);
        int*  cstart  = (int*)(ws + off_cstart);
        int*  ccursor = (int*)(ws + off_ccur);
        int*  start   = (int*)(ws + off_start);

        hipMemsetAsync(cc, 0, (size_t)NCB * sizeof(int), stream);

        coarse_hist196<<<128, 1024, 0, stream>>>(row, cc, n_edges);
        scan_kernel<<<1, 1024, 0, stream>>>(cc, cstart, ccursor, NCB);
        const int cb = (n_edges + CHUNK - 1) / CHUNK;
        agg_scatter_kernel<<<cb, 256, 0, stream>>>(row, col, attr, ccursor, cw, n_edges);
        fine_scatter512_kernel<<<NCB, 1024, 0, stream>>>(cw, cstart, start, colw, n_nodes);

        const int waves_per_block = 4;                 // 256 threads
        const int nb = (n_nodes + waves_per_block - 1) / waves_per_block;
        gather_accum_kernel<<<nb, 256, 0, stream>>>(x, start, colw, out, n_nodes);
        return;
    }

    // ---------- legacy CSR layout (fallback #2) ----------
    size_t l_off_colw   = 0;
    size_t l_off_counts = l_off_colw + (size_t)n_edges * sizeof(int2);
    size_t l_off_start  = l_off_counts + (size_t)n_nodes * sizeof(int);
    size_t l_off_cursor = l_off_start + (size_t)(n_nodes + 1) * sizeof(int);
    size_t ws_needed_old = l_off_cursor + (size_t)n_nodes * sizeof(int);

    if (ws_size >= ws_needed_old) {
        char* ws = (char*)d_ws;
        int2* colw   = (int2*)(ws + l_off_colw);
        int*  counts = (int*)(ws + l_off_counts);
        int*  start  = (int*)(ws + l_off_start);
        int*  cursor = (int*)(ws + l_off_cursor);

        hipMemsetAsync(counts, 0, (size_t)n_nodes * sizeof(int), stream);

        const int eb = (n_edges + 255) / 256;
        hist_kernel<<<eb, 256, 0, stream>>>(row, counts, n_edges);
        scan_kernel<<<1, 1024, 0, stream>>>(counts, start, cursor, n_nodes);
        bucket_kernel<<<eb, 256, 0, stream>>>(row, col, attr, cursor, colw, n_edges);

        const int waves_per_block = 4;
        const int nb = (n_nodes + waves_per_block - 1) / waves_per_block;
        gather_accum_kernel<<<nb, 256, 0, stream>>>(x, start, colw, out, n_nodes);
        return;
    }

    // ---------- last resort: atomic kernel ----------
    hipMemsetAsync(out, 0, (size_t)out_size * sizeof(float), stream);
    const long long total = (long long)n_edges * 64;
    const int blocks = (int)((total + 255) / 256);
    spline_scatter_atomic<<<blocks, 256, 0, stream>>>(x, row, col, attr, out, n_edges);
}